// Round 4
// baseline (143.512 us; speedup 1.0000x reference)
//
#include <hip/hip_runtime.h>

// Problem: attention, q,k,v [B=4, N=2048, H=8, D=64] fp32 -> out same.
#define B 4
#define N 2048
#define H 8
#define D 64
#define HD 512              // row stride (elements) for fixed (b,h)
#define QT 256              // q rows per block (4 waves x 64)
#define KT 64               // keys per tile
#define NTILES (N / KT)     // 32
#define PLS 72              // prep-kernel LDS pad stride

typedef _Float16 half8 __attribute__((ext_vector_type(8)));
typedef float float4_ __attribute__((ext_vector_type(4)));
typedef float float16_ __attribute__((ext_vector_type(16)));

#define MFMA32(a, b, c) __builtin_amdgcn_mfma_f32_32x32x16_f16((a), (b), (c), 0, 0, 0)

// ---------------- fused prepass: K f32->f16 same layout; V -> Vt [b,h,d,n'] f16 ----------------
// Vt key axis is tau-permuted: position p holds original key tau(p), tau = swap bits 2<->3.
// tau makes the 32x32 MFMA S-tile D-rows line up with the PV A-operand k-slots per lane,
// so P never needs a cross-lane exchange (verified in R2).
__global__ void prep_kernel(const float* __restrict__ K, const float* __restrict__ V,
                            _Float16* __restrict__ Kf, _Float16* __restrict__ Vtr) {
    __shared__ _Float16 tile[64][PLS];
    const int t = threadIdx.x;
    if (blockIdx.x < 2048) {
        const size_t i = (size_t)blockIdx.x * 256 + t;
        const float4_* p = (const float4_*)(K + i * 8);
        float4_ a = p[0], b = p[1];
        half8 hh;
        #pragma unroll
        for (int j = 0; j < 4; ++j) { hh[j] = (_Float16)a[j]; hh[4 + j] = (_Float16)b[j]; }
        *(half8*)(Kf + i * 8) = hh;
    } else {
        const int bid = blockIdx.x - 2048;
        const int nt = bid & 31, h = (bid >> 5) & 7, b = bid >> 8;
        {
            const int i = t >> 2, c0 = (t & 3) * 16;
            const float* vp = V + (size_t)b * N * HD + (size_t)(nt * 64 + i) * HD + h * D + c0;
            #pragma unroll
            for (int j = 0; j < 4; ++j) {
                float4_ a = *(const float4_*)(vp + j * 4);
                #pragma unroll
                for (int c = 0; c < 4; ++c) tile[i][c0 + j * 4 + c] = (_Float16)a[c];
            }
        }
        __syncthreads();
        {
            const int d = t >> 2, n0 = (t & 3) * 16;
            // tau within the 16-run: positions n0+0..7 hold keys n0+{0,1,2,3,8,9,10,11};
            //                        positions n0+8..15 hold keys n0+{4,5,6,7,12,13,14,15}.
            half8 w0, w1;
            #pragma unroll
            for (int j = 0; j < 4; ++j) {
                w0[j]     = tile[n0 + j][d];
                w0[4 + j] = tile[n0 + 8 + j][d];
                w1[j]     = tile[n0 + 4 + j][d];
                w1[4 + j] = tile[n0 + 12 + j][d];
            }
            _Float16* op = Vtr + ((size_t)(b * H + h) * D + d) * N + nt * 64 + n0;
            *(half8*)op = w0;
            *(half8*)(op + 8) = w1;
        }
    }
}

// ---------------- async staging (chunk-swizzled, wave-split); 2 gloads each = 4/tile/wave ----
__device__ __forceinline__ void stage_k(const _Float16* __restrict__ Kbh, int keybase,
                                        _Float16* kb, int wave, int lane) {
    const int rsub = lane >> 3, slot = lane & 7;
    #pragma unroll
    for (int i = 0; i < 2; ++i) {
        const int row = wave * 16 + i * 8 + rsub;
        const int c = slot ^ (row & 7);
        __builtin_amdgcn_global_load_lds(
            (const __attribute__((address_space(1))) void*)(Kbh + (size_t)(keybase + row) * HD + c * 8),
            (__attribute__((address_space(3))) void*)(kb + (wave * 16 + i * 8) * 64), 16, 0, 0);
    }
}
__device__ __forceinline__ void stage_v(const _Float16* __restrict__ Vbh, int keybase,
                                        _Float16* vb, int wave, int lane) {
    const int rsub = lane >> 3, slot = lane & 7;
    #pragma unroll
    for (int i = 0; i < 2; ++i) {
        const int row = wave * 16 + i * 8 + rsub;      // d row
        const int c = slot ^ (row & 7);
        __builtin_amdgcn_global_load_lds(
            (const __attribute__((address_space(1))) void*)(Vbh + (size_t)row * N + keybase + c * 8),
            (__attribute__((address_space(3))) void*)(vb + (wave * 16 + i * 8) * 64), 16, 0, 0);
    }
}

// ---------------- main: 4 waves x 64 q-rows, triple-buffered K/V, counted vmcnt ----------------
__global__ __launch_bounds__(256, 1)
void fattn8_kernel(const float* __restrict__ Q, const _Float16* __restrict__ Kf,
                   const _Float16* __restrict__ Vt, float* __restrict__ Out)
{
    // separate arrays (not [3][..]) to help alias analysis keep stage/read independent
    __shared__ __align__(16) _Float16 KbA[KT * 64], KbB[KT * 64], KbC[KT * 64];
    __shared__ __align__(16) _Float16 VbA[D * 64],  VbB[D * 64],  VbC[D * 64];

    const int tid  = threadIdx.x;
    const int wave = tid >> 6;
    const int lane = tid & 63;
    const int ln   = lane & 31;
    const int hi   = lane >> 5;

    const int h = blockIdx.y;
    const int b = blockIdx.z;
    const int q_base = blockIdx.x * QT + wave * 64;   // wave owns 64 q-rows (2 qb-blocks of 32)

    const size_t bh_q = (size_t)b * N * HD + (size_t)h * D;
    const _Float16* Kbh = Kf + bh_q;
    const _Float16* Vbh = Vt + (size_t)(b * H + h) * D * N;

    // Q rows in registers as S^T B-frags: qf[qb][ks][j] = Q[q_base+qb*32+ln][ks*16+hi*8+j]*SC
    const float SC = 0.125f * 1.4426950408889634f;
    half8 qf[2][4];
    #pragma unroll
    for (int qb = 0; qb < 2; ++qb) {
        const float* qp = Q + bh_q + (size_t)(q_base + qb * 32 + ln) * HD + hi * 8;
        #pragma unroll
        for (int ks = 0; ks < 4; ++ks) {
            float4_ a0 = *(const float4_*)(qp + ks * 16);
            float4_ a1 = *(const float4_*)(qp + ks * 16 + 4);
            half8 f;
            #pragma unroll
            for (int j = 0; j < 4; ++j) { f[j] = (_Float16)(a0[j] * SC); f[4 + j] = (_Float16)(a1[j] * SC); }
            qf[qb][ks] = f;
        }
    }

    float16_ o[2][2] = {};          // [qb][d-half]
    float lsum[2] = {0.f, 0.f};

    // prologue: stage tiles 0 and 1 (4 vmem ops per tile per wave)
    _Float16 *kc = KbA, *kn = KbB, *kf = KbC;
    _Float16 *vc = VbA, *vn = VbB, *vf = VbC;
    stage_k(Kbh, 0, kc, wave, lane);  stage_v(Vbh, 0, vc, wave, lane);
    stage_k(Kbh, KT, kn, wave, lane); stage_v(Vbh, KT, vn, wave, lane);

    for (int t = 0; t < NTILES; ++t) {
        // retire tile t's staging (4 newest = tile t+1 may stay in flight); then block-wide
        // barrier makes (a) tile t fully visible from all waves' loads, (b) buffer kf/vf free.
        if (t < NTILES - 1) asm volatile("s_waitcnt vmcnt(4)" ::: "memory");
        else                asm volatile("s_waitcnt vmcnt(0)" ::: "memory");
        __builtin_amdgcn_s_barrier();
        __builtin_amdgcn_sched_barrier(0);     // pin ds_reads below the barrier (rule-18 class)
        if (t + 2 < NTILES) {
            stage_k(Kbh, (t + 2) * KT, kf, wave, lane);
            stage_v(Vbh, (t + 2) * KT, vf, wave, lane);
        }

        // ---- S(t): S^T = K (Q*sc)^T, 32x32x16, K-frags shared across both qb ----
        half8 pf[2][4];
        #pragma unroll
        for (int kb = 0; kb < 2; ++kb) {
            float16_ s0 = {}, s1 = {};
            __builtin_amdgcn_s_setprio(1);
            #pragma unroll
            for (int ks = 0; ks < 4; ++ks) {
                const int csw = ((2 * ks + hi) ^ (ln & 7)) * 8;
                half8 a = *(const half8*)(kc + (kb * 32 + ln) * 64 + csw);
                s0 = MFMA32(a, qf[0][ks], s0);
                s1 = MFMA32(a, qf[1][ks], s1);
            }
            __builtin_amdgcn_s_setprio(0);
            #pragma unroll
            for (int qb = 0; qb < 2; ++qb) {
                const float16_ s = qb ? s1 : s0;    // qb is unroll-constant
                half8 f0, f1;
                #pragma unroll
                for (int j = 0; j < 8; ++j) {
                    float pa = __builtin_amdgcn_exp2f(s[j]);
                    float pb = __builtin_amdgcn_exp2f(s[8 + j]);
                    lsum[qb] += pa + pb;
                    f0[j] = (_Float16)pa;
                    f1[j] = (_Float16)pb;
                }
                pf[qb][2 * kb]     = f0;
                pf[qb][2 * kb + 1] = f1;
            }
        }

        // ---- PV(t): V-frags shared across both qb ----
        __builtin_amdgcn_s_setprio(1);
        #pragma unroll
        for (int ks = 0; ks < 4; ++ks) {
            const int csw = ((2 * ks + hi) ^ (ln & 7)) * 8;
            half8 b0 = *(const half8*)(vc + ln * 64 + csw);
            half8 b1 = *(const half8*)(vc + (32 + ln) * 64 + csw);
            o[0][0] = MFMA32(pf[0][ks], b0, o[0][0]);
            o[0][1] = MFMA32(pf[0][ks], b1, o[0][1]);
            o[1][0] = MFMA32(pf[1][ks], b0, o[1][0]);
            o[1][1] = MFMA32(pf[1][ks], b1, o[1][1]);
        }
        __builtin_amdgcn_s_setprio(0);

        // rotate buffers: consumed one becomes the next free slot
        _Float16* tk = kc; kc = kn; kn = kf; kf = tk;
        _Float16* tv = vc; vc = vn; vn = vf; vf = tv;
    }

    // finalize: per-lane row sums (q = qb*32 + ln, split by hi); combine halves, store
    #pragma unroll
    for (int qb = 0; qb < 2; ++qb) {
        float v = lsum[qb];
        v += __shfl_xor(v, 32, 64);
        const float inv = 1.0f / v;
        #pragma unroll
        for (int r = 0; r < 16; ++r) {
            const int rl = (r & 3) + 8 * (r >> 2) + 4 * hi;
            const float linv = __shfl(inv, rl, 64);
            const size_t ro = bh_q + (size_t)(q_base + qb * 32 + rl) * HD;
            Out[ro + ln]      = o[qb][0][r] * linv;
            Out[ro + 32 + ln] = o[qb][1][r] * linv;
        }
    }
}

// ---------------- fallback (round-1 verified kernel) if ws too small ----------------
__global__ __launch_bounds__(256, 2)
void fattn_fb_kernel(const float* __restrict__ Q, const float* __restrict__ K,
                     const float* __restrict__ V, float* __restrict__ Out)
{
    __shared__ __align__(16) _Float16 Ks[KT][PLS];
    __shared__ __align__(16) _Float16 Vts[D][PLS];
    __shared__ __align__(16) _Float16 Pwf[4][16][PLS];
    const int tid = threadIdx.x, wave = tid >> 6, lane = tid & 63;
    const int m = lane & 15, quad = lane >> 4;
    const int q_base = blockIdx.x * 64;
    const size_t bh_off = ((size_t)blockIdx.z * N * H + (size_t)blockIdx.y) * D;
    const float SCALE = 0.125f;
    const int qrow = q_base + wave * 16 + m;
    const float* qp = Q + bh_off + (size_t)qrow * HD + quad * 8;
    half8 qf0, qf1;
    #pragma unroll
    for (int j = 0; j < 8; ++j) qf0[j] = (_Float16)(qp[j] * SCALE);
    #pragma unroll
    for (int j = 0; j < 8; ++j) qf1[j] = (_Float16)(qp[32 + j] * SCALE);
    float4_ o[4] = {};
    float mi[4], li[4];
    #pragma unroll
    for (int r = 0; r < 4; ++r) { mi[r] = -1e30f; li[r] = 0.0f; }
    for (int kt = 0; kt < N; kt += KT) {
        __syncthreads();
        {
            const int key = tid >> 2, c0 = (tid & 3) * 16;
            const float* kp = K + bh_off + (size_t)(kt + key) * HD + c0;
            half8 lo, hi;
            #pragma unroll
            for (int j = 0; j < 8; ++j) lo[j] = (_Float16)kp[j];
            #pragma unroll
            for (int j = 0; j < 8; ++j) hi[j] = (_Float16)kp[8 + j];
            *(half8*)&Ks[key][c0] = lo;
            *(half8*)&Ks[key][c0 + 8] = hi;
        }
        {
            const int c0 = (tid & 15) * 4, k0 = (tid >> 4) * 4;
            const float* vp = V + bh_off + (size_t)(kt + k0) * HD + c0;
            #pragma unroll
            for (int c = 0; c < 4; ++c)
                #pragma unroll
                for (int i = 0; i < 4; ++i)
                    Vts[c0 + c][k0 + i] = (_Float16)vp[i * HD + c];
        }
        __syncthreads();
        float4_ s[4];
        #pragma unroll
        for (int blk = 0; blk < 4; ++blk) {
            const int key = blk * 16 + m;
            half8 kf0 = *(const half8*)&Ks[key][quad * 8];
            half8 kf1 = *(const half8*)&Ks[key][32 + quad * 8];
            float4_ acc = {};
            acc = __builtin_amdgcn_mfma_f32_16x16x32_f16(qf0, kf0, acc, 0, 0, 0);
            acc = __builtin_amdgcn_mfma_f32_16x16x32_f16(qf1, kf1, acc, 0, 0, 0);
            s[blk] = acc;
        }
        float alpha[4];
        #pragma unroll
        for (int r = 0; r < 4; ++r) {
            float v0 = fmaxf(fmaxf(s[0][r], s[1][r]), fmaxf(s[2][r], s[3][r]));
            #pragma unroll
            for (int mask = 1; mask < 16; mask <<= 1) v0 = fmaxf(v0, __shfl_xor(v0, mask, 64));
            float mn = fmaxf(mi[r], v0);
            alpha[r] = __expf(mi[r] - mn);
            mi[r] = mn;
        }
        #pragma unroll
        for (int blk = 0; blk < 4; ++blk)
            #pragma unroll
            for (int r = 0; r < 4; ++r) s[blk][r] = __expf(s[blk][r] - mi[r]);
        #pragma unroll
        for (int r = 0; r < 4; ++r) {
            float tt = s[0][r] + s[1][r] + s[2][r] + s[3][r];
            #pragma unroll
            for (int mask = 1; mask < 16; mask <<= 1) tt += __shfl_xor(tt, mask, 64);
            li[r] = li[r] * alpha[r] + tt;
        }
        #pragma unroll
        for (int d = 0; d < 4; ++d)
            #pragma unroll
            for (int r = 0; r < 4; ++r) o[d][r] *= alpha[r];
        #pragma unroll
        for (int blk = 0; blk < 4; ++blk)
            #pragma unroll
            for (int r = 0; r < 4; ++r)
                Pwf[wave][quad * 4 + r][blk * 16 + m] = (_Float16)s[blk][r];
        #pragma unroll
        for (int ks = 0; ks < 2; ++ks) {
            half8 af = *(const half8*)&Pwf[wave][m][ks * 32 + quad * 8];
            #pragma unroll
            for (int d = 0; d < 4; ++d) {
                half8 bf = *(const half8*)&Vts[d * 16 + m][ks * 32 + quad * 8];
                o[d] = __builtin_amdgcn_mfma_f32_16x16x32_f16(af, bf, o[d], 0, 0, 0);
            }
        }
    }
    #pragma unroll
    for (int d = 0; d < 4; ++d)
        #pragma unroll
        for (int r = 0; r < 4; ++r) {
            const int row = q_base + wave * 16 + quad * 4 + r;
            Out[bh_off + (size_t)row * HD + d * 16 + m] = o[d][r] / li[r];
        }
}

extern "C" void kernel_launch(void* const* d_in, const int* in_sizes, int n_in,
                              void* d_out, int out_size, void* d_ws, size_t ws_size,
                              hipStream_t stream) {
    const float* q = (const float*)d_in[0];
    const float* k = (const float*)d_in[1];
    const float* v = (const float*)d_in[2];
    float* out = (float*)d_out;

    const size_t nelem = (size_t)B * N * H * D;           // 4194304
    const size_t need = 2 * nelem * sizeof(_Float16);     // Kf + Vt

    if (ws_size >= need) {
        _Float16* Kf = (_Float16*)d_ws;
        _Float16* Vtr = Kf + nelem;
        prep_kernel<<<dim3(2048 + 1024), 256, 0, stream>>>(k, v, Kf, Vtr);
        fattn8_kernel<<<dim3(N / QT, H, B), 256, 0, stream>>>(q, Kf, Vtr, out);
    } else {
        fattn_fb_kernel<<<dim3(N / 64, H, B), 256, 0, stream>>>(q, k, v, out);
    }
}

// Round 5
// 136.054 us; speedup vs baseline: 1.0548x; 1.0548x over previous
//
#include <hip/hip_runtime.h>

// Problem: attention, q,k,v [B=4, N=2048, H=8, D=64] fp32 -> out same.
#define B 4
#define N 2048
#define H 8
#define D 64
#define HD 512              // row stride (elements) for fixed (b,h)
#define QT 256              // q rows per block (4 q-groups x 64, each done by 2 waves)
#define KT 64               // keys per tile
#define NT2 16              // tiles per key-half (split-K)
#define PLS 72              // prep-kernel LDS pad stride

typedef _Float16 half8 __attribute__((ext_vector_type(8)));
typedef float float4_ __attribute__((ext_vector_type(4)));
typedef float float16_ __attribute__((ext_vector_type(16)));

#define MFMA32(a, b, c) __builtin_amdgcn_mfma_f32_32x32x16_f16((a), (b), (c), 0, 0, 0)

// ---------------- fused prepass: K f32->f16 same layout; V -> Vt [b,h,d,n'] f16 ----------------
// Vt key axis is tau-permuted: position p holds original key tau(p), tau = swap bits 2<->3.
// tau makes the 32x32 MFMA S-tile D-rows line up with the PV A-operand k-slots per lane,
// so P never needs a cross-lane exchange (verified in R2).
__global__ void prep_kernel(const float* __restrict__ K, const float* __restrict__ V,
                            _Float16* __restrict__ Kf, _Float16* __restrict__ Vtr) {
    __shared__ _Float16 tile[64][PLS];
    const int t = threadIdx.x;
    if (blockIdx.x < 2048) {
        const size_t i = (size_t)blockIdx.x * 256 + t;
        const float4_* p = (const float4_*)(K + i * 8);
        float4_ a = p[0], b = p[1];
        half8 hh;
        #pragma unroll
        for (int j = 0; j < 4; ++j) { hh[j] = (_Float16)a[j]; hh[4 + j] = (_Float16)b[j]; }
        *(half8*)(Kf + i * 8) = hh;
    } else {
        const int bid = blockIdx.x - 2048;
        const int nt = bid & 31, h = (bid >> 5) & 7, b = bid >> 8;
        {
            const int i = t >> 2, c0 = (t & 3) * 16;
            const float* vp = V + (size_t)b * N * HD + (size_t)(nt * 64 + i) * HD + h * D + c0;
            #pragma unroll
            for (int j = 0; j < 4; ++j) {
                float4_ a = *(const float4_*)(vp + j * 4);
                #pragma unroll
                for (int c = 0; c < 4; ++c) tile[i][c0 + j * 4 + c] = (_Float16)a[c];
            }
        }
        __syncthreads();
        {
            const int d = t >> 2, n0 = (t & 3) * 16;
            // tau within the 16-run: positions n0+0..7 hold keys n0+{0,1,2,3,8,9,10,11};
            //                        positions n0+8..15 hold keys n0+{4,5,6,7,12,13,14,15}.
            half8 w0, w1;
            #pragma unroll
            for (int j = 0; j < 4; ++j) {
                w0[j]     = tile[n0 + j][d];
                w0[4 + j] = tile[n0 + 8 + j][d];
                w1[j]     = tile[n0 + 4 + j][d];
                w1[4 + j] = tile[n0 + 12 + j][d];
            }
            _Float16* op = Vtr + ((size_t)(b * H + h) * D + d) * N + nt * 64 + n0;
            *(half8*)op = w0;
            *(half8*)(op + 8) = w1;
        }
    }
}

// ------- async staging (chunk-swizzled, group-split); wg in [0,4) covers 16 rows each -------
__device__ __forceinline__ void stage_k(const _Float16* __restrict__ Kbh, int keybase,
                                        _Float16* kb, int wg, int lane) {
    const int rsub = lane >> 3, slot = lane & 7;
    #pragma unroll
    for (int i = 0; i < 2; ++i) {
        const int row = wg * 16 + i * 8 + rsub;
        const int c = slot ^ (row & 7);
        __builtin_amdgcn_global_load_lds(
            (const __attribute__((address_space(1))) void*)(Kbh + (size_t)(keybase + row) * HD + c * 8),
            (__attribute__((address_space(3))) void*)(kb + (wg * 16 + i * 8) * 64), 16, 0, 0);
    }
}
__device__ __forceinline__ void stage_v(const _Float16* __restrict__ Vbh, int keybase,
                                        _Float16* vb, int wg, int lane) {
    const int rsub = lane >> 3, slot = lane & 7;
    #pragma unroll
    for (int i = 0; i < 2; ++i) {
        const int row = wg * 16 + i * 8 + rsub;      // d row
        const int c = slot ^ (row & 7);
        __builtin_amdgcn_global_load_lds(
            (const __attribute__((address_space(1))) void*)(Vbh + (size_t)row * N + keybase + c * 8),
            (__attribute__((address_space(3))) void*)(vb + (wg * 16 + i * 8) * 64), 16, 0, 0);
    }
}

// ---------------- main: split-K, 8 waves (4 q-groups x 2 key-halves), counted vmcnt ----------------
__global__ __launch_bounds__(512, 1)
void fattn9_kernel(const float* __restrict__ Q, const _Float16* __restrict__ Kf,
                   const _Float16* __restrict__ Vt, float* __restrict__ Out)
{
    // 96 KB: 2 streams x 3 K-buffers + 2 streams x 3 V-buffers (4096 halves each).
    // The combine epilogue reuses this space as float scratch (66 KB needed).
    static __shared__ __align__(16) _Float16 smem[49152];

    const int tid  = threadIdx.x;
    const int wave = tid >> 6;
    const int lane = tid & 63;
    const int ln   = lane & 31;
    const int hi   = lane >> 5;
    const int qg   = wave & 3;      // q-group: 64 q-rows
    const int kh   = wave >> 2;     // key-half: tiles [kh*16, kh*16+16)

    const int h = blockIdx.y;
    const int b = blockIdx.z;
    const int q_base = blockIdx.x * QT + qg * 64;

    const size_t bh_q = (size_t)b * N * HD + (size_t)h * D;
    const _Float16* Kbh = Kf + bh_q;
    const _Float16* Vbh = Vt + (size_t)(b * H + h) * D * N;

    _Float16* Kbuf = smem + kh * 12288;          // stream-local 3 x 4096
    _Float16* Vbuf = smem + 24576 + kh * 12288;
    _Float16 *kc = Kbuf, *kn = Kbuf + 4096, *kf = Kbuf + 8192;
    _Float16 *vc = Vbuf, *vn = Vbuf + 4096, *vf = Vbuf + 8192;

    // Q rows in registers as S^T B-frags: qf[qb][ks][j] = Q[q_base+qb*32+ln][ks*16+hi*8+j]*SC
    const float SC = 0.125f * 1.4426950408889634f;
    half8 qf[2][4];
    #pragma unroll
    for (int qb = 0; qb < 2; ++qb) {
        const float* qp = Q + bh_q + (size_t)(q_base + qb * 32 + ln) * HD + hi * 8;
        #pragma unroll
        for (int ks = 0; ks < 4; ++ks) {
            float4_ a0 = *(const float4_*)(qp + ks * 16);
            float4_ a1 = *(const float4_*)(qp + ks * 16 + 4);
            half8 f;
            #pragma unroll
            for (int j = 0; j < 4; ++j) { f[j] = (_Float16)(a0[j] * SC); f[4 + j] = (_Float16)(a1[j] * SC); }
            qf[qb][ks] = f;
        }
    }

    float16_ o[2][2] = {};          // [qb][d-half]
    float lsum[2] = {0.f, 0.f};

    // prologue: stage this stream's tiles 0 and 1 (4 vmem ops per tile per wave)
    const int tbase = kh * NT2 * KT;
    stage_k(Kbh, tbase, kc, qg, lane);          stage_v(Vbh, tbase, vc, qg, lane);
    stage_k(Kbh, tbase + KT, kn, qg, lane);     stage_v(Vbh, tbase + KT, vn, qg, lane);

    for (int t = 0; t < NT2; ++t) {
        // retire own tile t's staging (tile t+1's 4 loads may stay in flight); block barrier
        // then makes tile t visible from all 4 staging waves of this stream.
        if (t < NT2 - 1) asm volatile("s_waitcnt vmcnt(4)" ::: "memory");
        else             asm volatile("s_waitcnt vmcnt(0)" ::: "memory");
        __builtin_amdgcn_s_barrier();
        __builtin_amdgcn_sched_barrier(0);     // pin ds_reads below the barrier
        if (t + 2 < NT2) {
            stage_k(Kbh, tbase + (t + 2) * KT, kf, qg, lane);
            stage_v(Vbh, tbase + (t + 2) * KT, vf, qg, lane);
        }

        // ---- S(t): S^T = K (Q*sc)^T, 32x32x16, K-frags shared across both qb ----
        half8 pf[2][4];
        #pragma unroll
        for (int kb = 0; kb < 2; ++kb) {
            float16_ s0 = {}, s1 = {};
            __builtin_amdgcn_s_setprio(1);
            #pragma unroll
            for (int ks = 0; ks < 4; ++ks) {
                const int csw = ((2 * ks + hi) ^ (ln & 7)) * 8;
                half8 a = *(const half8*)(kc + (kb * 32 + ln) * 64 + csw);
                s0 = MFMA32(a, qf[0][ks], s0);
                s1 = MFMA32(a, qf[1][ks], s1);
            }
            __builtin_amdgcn_s_setprio(0);
            #pragma unroll
            for (int qb = 0; qb < 2; ++qb) {
                const float16_ s = qb ? s1 : s0;    // qb is unroll-constant
                half8 f0, f1;
                #pragma unroll
                for (int j = 0; j < 8; ++j) {
                    float pa = __builtin_amdgcn_exp2f(s[j]);
                    float pb = __builtin_amdgcn_exp2f(s[8 + j]);
                    lsum[qb] += pa + pb;
                    f0[j] = (_Float16)pa;
                    f1[j] = (_Float16)pb;
                }
                pf[qb][2 * kb]     = f0;
                pf[qb][2 * kb + 1] = f1;
            }
        }

        // ---- PV(t): V-frags shared across both qb ----
        __builtin_amdgcn_s_setprio(1);
        #pragma unroll
        for (int ks = 0; ks < 4; ++ks) {
            const int csw = ((2 * ks + hi) ^ (ln & 7)) * 8;
            half8 b0 = *(const half8*)(vc + ln * 64 + csw);
            half8 b1 = *(const half8*)(vc + (32 + ln) * 64 + csw);
            o[0][0] = MFMA32(pf[0][ks], b0, o[0][0]);
            o[0][1] = MFMA32(pf[0][ks], b1, o[0][1]);
            o[1][0] = MFMA32(pf[1][ks], b0, o[1][0]);
            o[1][1] = MFMA32(pf[1][ks], b1, o[1][1]);
        }
        __builtin_amdgcn_s_setprio(0);

        // rotate buffers
        _Float16* tk = kc; kc = kn; kn = kf; kf = tk;
        _Float16* tv = vc; vc = vn; vn = vf; vf = tv;
    }

    // ---- combine epilogue: sum the two key-half partials through LDS ----
    __syncthreads();                           // all waves done reading K/V LDS
    float* cb = (float*)smem;                  // [qg][qb][dh][r][lane] = 16384 floats
    float* ls = cb + 4 * 2 * 2 * 16 * 64;      // [qg][qb][lane] = 512 floats
    if (kh == 1) {
        #pragma unroll
        for (int qb = 0; qb < 2; ++qb) {
            #pragma unroll
            for (int dh = 0; dh < 2; ++dh)
                #pragma unroll
                for (int r = 0; r < 16; ++r)
                    cb[(((qg * 2 + qb) * 2 + dh) * 16 + r) * 64 + lane] = o[qb][dh][r];
            ls[(qg * 2 + qb) * 64 + lane] = lsum[qb];
        }
    }
    __syncthreads();
    if (kh == 0) {
        #pragma unroll
        for (int qb = 0; qb < 2; ++qb) {
            #pragma unroll
            for (int dh = 0; dh < 2; ++dh)
                #pragma unroll
                for (int r = 0; r < 16; ++r)
                    o[qb][dh][r] += cb[(((qg * 2 + qb) * 2 + dh) * 16 + r) * 64 + lane];
            lsum[qb] += ls[(qg * 2 + qb) * 64 + lane];
        }
        // finalize: per-lane row sums (q = qb*32 + ln, split by hi); combine halves, store
        #pragma unroll
        for (int qb = 0; qb < 2; ++qb) {
            float v = lsum[qb];
            v += __shfl_xor(v, 32, 64);
            const float inv = 1.0f / v;
            #pragma unroll
            for (int r = 0; r < 16; ++r) {
                const int rl = (r & 3) + 8 * (r >> 2) + 4 * hi;
                const float linv = __shfl(inv, rl, 64);
                const size_t ro = bh_q + (size_t)(q_base + qb * 32 + rl) * HD;
                Out[ro + ln]      = o[qb][0][r] * linv;
                Out[ro + 32 + ln] = o[qb][1][r] * linv;
            }
        }
    }
}

// ---------------- fallback (round-1 verified kernel) if ws too small ----------------
__global__ __launch_bounds__(256, 2)
void fattn_fb_kernel(const float* __restrict__ Q, const float* __restrict__ K,
                     const float* __restrict__ V, float* __restrict__ Out)
{
    __shared__ __align__(16) _Float16 Ks[KT][PLS];
    __shared__ __align__(16) _Float16 Vts[D][PLS];
    __shared__ __align__(16) _Float16 Pwf[4][16][PLS];
    const int tid = threadIdx.x, wave = tid >> 6, lane = tid & 63;
    const int m = lane & 15, quad = lane >> 4;
    const int q_base = blockIdx.x * 64;
    const size_t bh_off = ((size_t)blockIdx.z * N * H + (size_t)blockIdx.y) * D;
    const float SCALE = 0.125f;
    const int qrow = q_base + wave * 16 + m;
    const float* qp = Q + bh_off + (size_t)qrow * HD + quad * 8;
    half8 qf0, qf1;
    #pragma unroll
    for (int j = 0; j < 8; ++j) qf0[j] = (_Float16)(qp[j] * SCALE);
    #pragma unroll
    for (int j = 0; j < 8; ++j) qf1[j] = (_Float16)(qp[32 + j] * SCALE);
    float4_ o[4] = {};
    float mi[4], li[4];
    #pragma unroll
    for (int r = 0; r < 4; ++r) { mi[r] = -1e30f; li[r] = 0.0f; }
    for (int kt = 0; kt < N; kt += KT) {
        __syncthreads();
        {
            const int key = tid >> 2, c0 = (tid & 3) * 16;
            const float* kp = K + bh_off + (size_t)(kt + key) * HD + c0;
            half8 lo, hi;
            #pragma unroll
            for (int j = 0; j < 8; ++j) lo[j] = (_Float16)kp[j];
            #pragma unroll
            for (int j = 0; j < 8; ++j) hi[j] = (_Float16)kp[8 + j];
            *(half8*)&Ks[key][c0] = lo;
            *(half8*)&Ks[key][c0 + 8] = hi;
        }
        {
            const int c0 = (tid & 15) * 4, k0 = (tid >> 4) * 4;
            const float* vp = V + bh_off + (size_t)(kt + k0) * HD + c0;
            #pragma unroll
            for (int c = 0; c < 4; ++c)
                #pragma unroll
                for (int i = 0; i < 4; ++i)
                    Vts[c0 + c][k0 + i] = (_Float16)vp[i * HD + c];
        }
        __syncthreads();
        float4_ s[4];
        #pragma unroll
        for (int blk = 0; blk < 4; ++blk) {
            const int key = blk * 16 + m;
            half8 kf0 = *(const half8*)&Ks[key][quad * 8];
            half8 kf1 = *(const half8*)&Ks[key][32 + quad * 8];
            float4_ acc = {};
            acc = __builtin_amdgcn_mfma_f32_16x16x32_f16(qf0, kf0, acc, 0, 0, 0);
            acc = __builtin_amdgcn_mfma_f32_16x16x32_f16(qf1, kf1, acc, 0, 0, 0);
            s[blk] = acc;
        }
        float alpha[4];
        #pragma unroll
        for (int r = 0; r < 4; ++r) {
            float v0 = fmaxf(fmaxf(s[0][r], s[1][r]), fmaxf(s[2][r], s[3][r]));
            #pragma unroll
            for (int mask = 1; mask < 16; mask <<= 1) v0 = fmaxf(v0, __shfl_xor(v0, mask, 64));
            float mn = fmaxf(mi[r], v0);
            alpha[r] = __expf(mi[r] - mn);
            mi[r] = mn;
        }
        #pragma unroll
        for (int blk = 0; blk < 4; ++blk)
            #pragma unroll
            for (int r = 0; r < 4; ++r) s[blk][r] = __expf(s[blk][r] - mi[r]);
        #pragma unroll
        for (int r = 0; r < 4; ++r) {
            float tt = s[0][r] + s[1][r] + s[2][r] + s[3][r];
            #pragma unroll
            for (int mask = 1; mask < 16; mask <<= 1) tt += __shfl_xor(tt, mask, 64);
            li[r] = li[r] * alpha[r] + tt;
        }
        #pragma unroll
        for (int d = 0; d < 4; ++d)
            #pragma unroll
            for (int r = 0; r < 4; ++r) o[d][r] *= alpha[r];
        #pragma unroll
        for (int blk = 0; blk < 4; ++blk)
            #pragma unroll
            for (int r = 0; r < 4; ++r)
                Pwf[wave][quad * 4 + r][blk * 16 + m] = (_Float16)s[blk][r];
        #pragma unroll
        for (int ks = 0; ks < 2; ++ks) {
            half8 af = *(const half8*)&Pwf[wave][m][ks * 32 + quad * 8];
            #pragma unroll
            for (int d = 0; d < 4; ++d) {
                half8 bf = *(const half8*)&Vts[d * 16 + m][ks * 32 + quad * 8];
                o[d] = __builtin_amdgcn_mfma_f32_16x16x32_f16(af, bf, o[d], 0, 0, 0);
            }
        }
    }
    #pragma unroll
    for (int d = 0; d < 4; ++d)
        #pragma unroll
        for (int r = 0; r < 4; ++r) {
            const int row = q_base + wave * 16 + quad * 4 + r;
            Out[bh_off + (size_t)row * HD + d * 16 + m] = o[d][r] / li[r];
        }
}

extern "C" void kernel_launch(void* const* d_in, const int* in_sizes, int n_in,
                              void* d_out, int out_size, void* d_ws, size_t ws_size,
                              hipStream_t stream) {
    const float* q = (const float*)d_in[0];
    const float* k = (const float*)d_in[1];
    const float* v = (const float*)d_in[2];
    float* out = (float*)d_out;

    const size_t nelem = (size_t)B * N * H * D;           // 4194304
    const size_t need = 2 * nelem * sizeof(_Float16);     // Kf + Vt

    if (ws_size >= need) {
        _Float16* Kf = (_Float16*)d_ws;
        _Float16* Vtr = Kf + nelem;
        prep_kernel<<<dim3(2048 + 1024), 256, 0, stream>>>(k, v, Kf, Vtr);
        fattn9_kernel<<<dim3(N / QT, H, B), 512, 0, stream>>>(q, Kf, Vtr, out);
    } else {
        fattn_fb_kernel<<<dim3(N / 64, H, B), 256, 0, stream>>>(q, k, v, out);
    }
}

// Round 6
// 134.261 us; speedup vs baseline: 1.0689x; 1.0134x over previous
//
#include <hip/hip_runtime.h>

// Problem: attention, q,k,v [B=4, N=2048, H=8, D=64] fp32 -> out same.
#define B 4
#define N 2048
#define H 8
#define D 64
#define HD 512              // row stride (elements) for fixed (b,h)
#define QT 128              // q rows per block (4 q-groups x 32, x 2 key-halves)
#define KT 64               // keys per tile
#define NT2 16              // tiles per key-half (split-K)
#define PLS 72              // prep-kernel LDS pad stride

typedef _Float16 half8 __attribute__((ext_vector_type(8)));
typedef float float4_ __attribute__((ext_vector_type(4)));
typedef float float16_ __attribute__((ext_vector_type(16)));

#define MFMA32(a, b, c) __builtin_amdgcn_mfma_f32_32x32x16_f16((a), (b), (c), 0, 0, 0)

// ---------------- fused prepass: K f32->f16 same layout; V -> Vt [b,h,d,n'] f16 ----------------
// Vt key axis is tau-permuted: position p holds original key tau(p), tau = swap bits 2<->3.
// tau makes the 32x32 MFMA S-tile D-rows line up with the PV A-operand k-slots per lane,
// so P never needs a cross-lane exchange (verified in R2).
__global__ void prep_kernel(const float* __restrict__ K, const float* __restrict__ V,
                            _Float16* __restrict__ Kf, _Float16* __restrict__ Vtr) {
    __shared__ _Float16 tile[64][PLS];
    const int t = threadIdx.x;
    if (blockIdx.x < 2048) {
        const size_t i = (size_t)blockIdx.x * 256 + t;
        const float4_* p = (const float4_*)(K + i * 8);
        float4_ a = p[0], b = p[1];
        half8 hh;
        #pragma unroll
        for (int j = 0; j < 4; ++j) { hh[j] = (_Float16)a[j]; hh[4 + j] = (_Float16)b[j]; }
        *(half8*)(Kf + i * 8) = hh;
    } else {
        const int bid = blockIdx.x - 2048;
        const int nt = bid & 31, h = (bid >> 5) & 7, b = bid >> 8;
        {
            const int i = t >> 2, c0 = (t & 3) * 16;
            const float* vp = V + (size_t)b * N * HD + (size_t)(nt * 64 + i) * HD + h * D + c0;
            #pragma unroll
            for (int j = 0; j < 4; ++j) {
                float4_ a = *(const float4_*)(vp + j * 4);
                #pragma unroll
                for (int c = 0; c < 4; ++c) tile[i][c0 + j * 4 + c] = (_Float16)a[c];
            }
        }
        __syncthreads();
        {
            const int d = t >> 2, n0 = (t & 3) * 16;
            // tau within the 16-run: positions n0+0..7 hold keys n0+{0,1,2,3,8,9,10,11};
            //                        positions n0+8..15 hold keys n0+{4,5,6,7,12,13,14,15}.
            half8 w0, w1;
            #pragma unroll
            for (int j = 0; j < 4; ++j) {
                w0[j]     = tile[n0 + j][d];
                w0[4 + j] = tile[n0 + 8 + j][d];
                w1[j]     = tile[n0 + 4 + j][d];
                w1[4 + j] = tile[n0 + 12 + j][d];
            }
            _Float16* op = Vtr + ((size_t)(b * H + h) * D + d) * N + nt * 64 + n0;
            *(half8*)op = w0;
            *(half8*)(op + 8) = w1;
        }
    }
}

// ------- async staging (chunk-swizzled, group-split); wg in [0,4) covers 16 rows each -------
__device__ __forceinline__ void stage_k(const _Float16* __restrict__ Kbh, int keybase,
                                        _Float16* kb, int wg, int lane) {
    const int rsub = lane >> 3, slot = lane & 7;
    #pragma unroll
    for (int i = 0; i < 2; ++i) {
        const int row = wg * 16 + i * 8 + rsub;
        const int c = slot ^ (row & 7);
        __builtin_amdgcn_global_load_lds(
            (const __attribute__((address_space(1))) void*)(Kbh + (size_t)(keybase + row) * HD + c * 8),
            (__attribute__((address_space(3))) void*)(kb + (wg * 16 + i * 8) * 64), 16, 0, 0);
    }
}
__device__ __forceinline__ void stage_v(const _Float16* __restrict__ Vbh, int keybase,
                                        _Float16* vb, int wg, int lane) {
    const int rsub = lane >> 3, slot = lane & 7;
    #pragma unroll
    for (int i = 0; i < 2; ++i) {
        const int row = wg * 16 + i * 8 + rsub;      // d row
        const int c = slot ^ (row & 7);
        __builtin_amdgcn_global_load_lds(
            (const __attribute__((address_space(1))) void*)(Vbh + (size_t)row * N + keybase + c * 8),
            (__attribute__((address_space(3))) void*)(vb + (wg * 16 + i * 8) * 64), 16, 0, 0);
    }
}

// ------- main: split-K, 8 waves (4 q-groups x 2 key-halves), dbuf + counted vmcnt, 2 blk/CU ----
__global__ __launch_bounds__(512, 4)
void fattn10_kernel(const float* __restrict__ Q, const _Float16* __restrict__ Kf,
                    const _Float16* __restrict__ Vt, float* __restrict__ Out)
{
    // 64 KB: 2 streams x 2 K-buffers + 2 streams x 2 V-buffers (4096 halves each).
    // Epilogue reuses it as float scratch (34 KB needed).
    static __shared__ __align__(16) _Float16 smem[32768];

    const int tid  = threadIdx.x;
    const int wave = tid >> 6;
    const int lane = tid & 63;
    const int ln   = lane & 31;
    const int hi   = lane >> 5;
    const int qg   = wave & 3;      // q-group: 32 q-rows
    const int kh   = wave >> 2;     // key-half: tiles [kh*16, kh*16+16)

    const int h = blockIdx.y;
    const int b = blockIdx.z;
    const int q_base = blockIdx.x * QT + qg * 32;

    const size_t bh_q = (size_t)b * N * HD + (size_t)h * D;
    const _Float16* Kbh = Kf + bh_q;
    const _Float16* Vbh = Vt + (size_t)(b * H + h) * D * N;

    _Float16* Kbuf = smem + kh * 8192;           // stream-local 2 x 4096
    _Float16* Vbuf = smem + 16384 + kh * 8192;

    // Q rows in registers as S^T B-frags: qf[ks][j] = Q[q_base+ln][ks*16+hi*8+j]*SC
    const float SC = 0.125f * 1.4426950408889634f;
    half8 qf[4];
    {
        const float* qp = Q + bh_q + (size_t)(q_base + ln) * HD + hi * 8;
        #pragma unroll
        for (int ks = 0; ks < 4; ++ks) {
            float4_ a0 = *(const float4_*)(qp + ks * 16);
            float4_ a1 = *(const float4_*)(qp + ks * 16 + 4);
            half8 f;
            #pragma unroll
            for (int j = 0; j < 4; ++j) { f[j] = (_Float16)(a0[j] * SC); f[4 + j] = (_Float16)(a1[j] * SC); }
            qf[ks] = f;
        }
    }

    float16_ o0 = {}, o1 = {};
    float lsum = 0.f;

    // prologue: stage this stream's tiles 0 and 1 (4 vmem ops per tile per wave)
    const int tbase = kh * NT2 * KT;
    stage_k(Kbh, tbase, Kbuf, qg, lane);              stage_v(Vbh, tbase, Vbuf, qg, lane);
    stage_k(Kbh, tbase + KT, Kbuf + 4096, qg, lane);  stage_v(Vbh, tbase + KT, Vbuf + 4096, qg, lane);

    for (int t = 0; t < NT2; ++t) {
        // counted retire: tile t's 4 loads are the oldest; tile t+1's 4 stay in flight.
        if (t < NT2 - 1) asm volatile("s_waitcnt vmcnt(4)" ::: "memory");
        else             asm volatile("s_waitcnt vmcnt(0)" ::: "memory");
        __builtin_amdgcn_s_barrier();          // all waves' tile-t staging now visible
        __builtin_amdgcn_sched_barrier(0);

        const _Float16* kc = Kbuf + (t & 1) * 4096;
        const _Float16* vc = Vbuf + (t & 1) * 4096;

        // ---- S(t): S^T = K (Q*sc)^T, 32x32x16 ----
        half8 pf[4];
        #pragma unroll
        for (int kb = 0; kb < 2; ++kb) {
            float16_ s = {};
            __builtin_amdgcn_s_setprio(1);
            #pragma unroll
            for (int ks = 0; ks < 4; ++ks) {
                const int csw = ((2 * ks + hi) ^ (ln & 7)) * 8;
                half8 a = *(const half8*)(kc + (kb * 32 + ln) * 64 + csw);
                s = MFMA32(a, qf[ks], s);
            }
            __builtin_amdgcn_s_setprio(0);
            half8 f0, f1;
            #pragma unroll
            for (int j = 0; j < 8; ++j) {
                float pa = __builtin_amdgcn_exp2f(s[j]);
                float pb = __builtin_amdgcn_exp2f(s[8 + j]);
                lsum += pa + pb;
                f0[j] = (_Float16)pa;
                f1[j] = (_Float16)pb;
            }
            pf[2 * kb]     = f0;
            pf[2 * kb + 1] = f1;
        }

        // ---- PV(t) ----
        __builtin_amdgcn_s_setprio(1);
        #pragma unroll
        for (int ks = 0; ks < 4; ++ks) {
            const int csw = ((2 * ks + hi) ^ (ln & 7)) * 8;
            half8 b0 = *(const half8*)(vc + ln * 64 + csw);
            half8 b1 = *(const half8*)(vc + (32 + ln) * 64 + csw);
            o0 = MFMA32(pf[ks], b0, o0);
            o1 = MFMA32(pf[ks], b1, o1);
        }
        __builtin_amdgcn_s_setprio(0);

        // end-of-phase: once every wave's reads of buf[t&1] are serviced (guaranteed: each
        // wave's lgkm waits precede its last MFMA, which precedes this barrier), overwrite it
        // with tile t+2. Issued here = in flight across the next phase (counted by vmcnt(4)).
        if (t + 2 < NT2) {
            __builtin_amdgcn_s_barrier();
            __builtin_amdgcn_sched_barrier(0);
            stage_k(Kbh, tbase + (t + 2) * KT, Kbuf + (t & 1) * 4096, qg, lane);
            stage_v(Vbh, tbase + (t + 2) * KT, Vbuf + (t & 1) * 4096, qg, lane);
        }
    }

    // ---- combine epilogue: sum the two key-half partials through LDS ----
    __syncthreads();                           // all waves done reading K/V LDS
    float* cb = (float*)smem;                  // [qg][dh][r][lane] = 8192 floats (32 KB)
    float* ls = cb + 4 * 2 * 16 * 64;          // [qg][lane] = 256 floats
    if (kh == 1) {
        #pragma unroll
        for (int r = 0; r < 16; ++r) {
            cb[((qg * 2 + 0) * 16 + r) * 64 + lane] = o0[r];
            cb[((qg * 2 + 1) * 16 + r) * 64 + lane] = o1[r];
        }
        ls[qg * 64 + lane] = lsum;
    }
    __syncthreads();
    if (kh == 0) {
        #pragma unroll
        for (int r = 0; r < 16; ++r) {
            o0[r] += cb[((qg * 2 + 0) * 16 + r) * 64 + lane];
            o1[r] += cb[((qg * 2 + 1) * 16 + r) * 64 + lane];
        }
        lsum += ls[qg * 64 + lane];
        // finalize: per-lane row sums (q = ln, split by hi); combine halves, store
        float v = lsum;
        v += __shfl_xor(v, 32, 64);
        const float inv = 1.0f / v;
        #pragma unroll
        for (int r = 0; r < 16; ++r) {
            const int rl = (r & 3) + 8 * (r >> 2) + 4 * hi;
            const float linv = __shfl(inv, rl, 64);
            const size_t ro = bh_q + (size_t)(q_base + rl) * HD;
            Out[ro + ln]      = o0[r] * linv;
            Out[ro + 32 + ln] = o1[r] * linv;
        }
    }
}

// ---------------- fallback (round-1 verified kernel) if ws too small ----------------
__global__ __launch_bounds__(256, 2)
void fattn_fb_kernel(const float* __restrict__ Q, const float* __restrict__ K,
                     const float* __restrict__ V, float* __restrict__ Out)
{
    __shared__ __align__(16) _Float16 Ks[KT][PLS];
    __shared__ __align__(16) _Float16 Vts[D][PLS];
    __shared__ __align__(16) _Float16 Pwf[4][16][PLS];
    const int tid = threadIdx.x, wave = tid >> 6, lane = tid & 63;
    const int m = lane & 15, quad = lane >> 4;
    const int q_base = blockIdx.x * 64;
    const size_t bh_off = ((size_t)blockIdx.z * N * H + (size_t)blockIdx.y) * D;
    const float SCALE = 0.125f;
    const int qrow = q_base + wave * 16 + m;
    const float* qp = Q + bh_off + (size_t)qrow * HD + quad * 8;
    half8 qf0, qf1;
    #pragma unroll
    for (int j = 0; j < 8; ++j) qf0[j] = (_Float16)(qp[j] * SCALE);
    #pragma unroll
    for (int j = 0; j < 8; ++j) qf1[j] = (_Float16)(qp[32 + j] * SCALE);
    float4_ o[4] = {};
    float mi[4], li[4];
    #pragma unroll
    for (int r = 0; r < 4; ++r) { mi[r] = -1e30f; li[r] = 0.0f; }
    for (int kt = 0; kt < N; kt += KT) {
        __syncthreads();
        {
            const int key = tid >> 2, c0 = (tid & 3) * 16;
            const float* kp = K + bh_off + (size_t)(kt + key) * HD + c0;
            half8 lo, hi;
            #pragma unroll
            for (int j = 0; j < 8; ++j) lo[j] = (_Float16)kp[j];
            #pragma unroll
            for (int j = 0; j < 8; ++j) hi[j] = (_Float16)kp[8 + j];
            *(half8*)&Ks[key][c0] = lo;
            *(half8*)&Ks[key][c0 + 8] = hi;
        }
        {
            const int c0 = (tid & 15) * 4, k0 = (tid >> 4) * 4;
            const float* vp = V + bh_off + (size_t)(kt + k0) * HD + c0;
            #pragma unroll
            for (int c = 0; c < 4; ++c)
                #pragma unroll
                for (int i = 0; i < 4; ++i)
                    Vts[c0 + c][k0 + i] = (_Float16)vp[i * HD + c];
        }
        __syncthreads();
        float4_ s[4];
        #pragma unroll
        for (int blk = 0; blk < 4; ++blk) {
            const int key = blk * 16 + m;
            half8 kf0 = *(const half8*)&Ks[key][quad * 8];
            half8 kf1 = *(const half8*)&Ks[key][32 + quad * 8];
            float4_ acc = {};
            acc = __builtin_amdgcn_mfma_f32_16x16x32_f16(qf0, kf0, acc, 0, 0, 0);
            acc = __builtin_amdgcn_mfma_f32_16x16x32_f16(qf1, kf1, acc, 0, 0, 0);
            s[blk] = acc;
        }
        float alpha[4];
        #pragma unroll
        for (int r = 0; r < 4; ++r) {
            float v0 = fmaxf(fmaxf(s[0][r], s[1][r]), fmaxf(s[2][r], s[3][r]));
            #pragma unroll
            for (int mask = 1; mask < 16; mask <<= 1) v0 = fmaxf(v0, __shfl_xor(v0, mask, 64));
            float mn = fmaxf(mi[r], v0);
            alpha[r] = __expf(mi[r] - mn);
            mi[r] = mn;
        }
        #pragma unroll
        for (int blk = 0; blk < 4; ++blk)
            #pragma unroll
            for (int r = 0; r < 4; ++r) s[blk][r] = __expf(s[blk][r] - mi[r]);
        #pragma unroll
        for (int r = 0; r < 4; ++r) {
            float tt = s[0][r] + s[1][r] + s[2][r] + s[3][r];
            #pragma unroll
            for (int mask = 1; mask < 16; mask <<= 1) tt += __shfl_xor(tt, mask, 64);
            li[r] = li[r] * alpha[r] + tt;
        }
        #pragma unroll
        for (int d = 0; d < 4; ++d)
            #pragma unroll
            for (int r = 0; r < 4; ++r) o[d][r] *= alpha[r];
        #pragma unroll
        for (int blk = 0; blk < 4; ++blk)
            #pragma unroll
            for (int r = 0; r < 4; ++r)
                Pwf[wave][quad * 4 + r][blk * 16 + m] = (_Float16)s[blk][r];
        #pragma unroll
        for (int ks = 0; ks < 2; ++ks) {
            half8 af = *(const half8*)&Pwf[wave][m][ks * 32 + quad * 8];
            #pragma unroll
            for (int d = 0; d < 4; ++d) {
                half8 bf = *(const half8*)&Vts[d * 16 + m][ks * 32 + quad * 8];
                o[d] = __builtin_amdgcn_mfma_f32_16x16x32_f16(af, bf, o[d], 0, 0, 0);
            }
        }
    }
    #pragma unroll
    for (int d = 0; d < 4; ++d)
        #pragma unroll
        for (int r = 0; r < 4; ++r) {
            const int row = q_base + wave * 16 + quad * 4 + r;
            Out[bh_off + (size_t)row * HD + d * 16 + m] = o[d][r] / li[r];
        }
}

extern "C" void kernel_launch(void* const* d_in, const int* in_sizes, int n_in,
                              void* d_out, int out_size, void* d_ws, size_t ws_size,
                              hipStream_t stream) {
    const float* q = (const float*)d_in[0];
    const float* k = (const float*)d_in[1];
    const float* v = (const float*)d_in[2];
    float* out = (float*)d_out;

    const size_t nelem = (size_t)B * N * H * D;           // 4194304
    const size_t need = 2 * nelem * sizeof(_Float16);     // Kf + Vt

    if (ws_size >= need) {
        _Float16* Kf = (_Float16*)d_ws;
        _Float16* Vtr = Kf + nelem;
        prep_kernel<<<dim3(2048 + 1024), 256, 0, stream>>>(k, v, Kf, Vtr);
        fattn10_kernel<<<dim3(N / QT, H, B), 512, 0, stream>>>(q, Kf, Vtr, out);
    } else {
        fattn_fb_kernel<<<dim3(N / 64, H, B), 256, 0, stream>>>(q, k, v, out);
    }
}